// Round 2
// baseline (159.153 us; speedup 1.0000x reference)
//
#include <hip/hip_runtime.h>
#include <stdint.h>

#define B_ROWS 4096
#define C_OUT  2048
#define C_IN   2048
#define EPS    1e-5f

typedef __attribute__((ext_vector_type(8))) short bf16x8;  // 8 bf16 = 4 VGPRs
typedef __attribute__((ext_vector_type(4))) float f32x4;

// RNE f32 -> bf16
__device__ __forceinline__ unsigned short f2bf(float f) {
    uint32_t u = __float_as_uint(f);
    uint32_t r = (u + 0x7fffu + ((u >> 16) & 1u)) >> 16;
    return (unsigned short)r;
}

// One launch converts both x and w (f32 -> bf16, float4-granular)
__global__ void cvt_f32_bf16_kernel(const float* __restrict__ x,
                                    const float* __restrict__ w,
                                    unsigned short* __restrict__ xb,
                                    unsigned short* __restrict__ wb,
                                    int nx4, int nw4) {
    int i = blockIdx.x * blockDim.x + threadIdx.x;
    const float* src;
    unsigned short* dst;
    if (i < nx4) {
        src = x; dst = xb;
    } else {
        i -= nx4;
        if (i >= nw4) return;
        src = w; dst = wb;
    }
    float4 v = ((const float4*)src)[i];
    ushort4 o;
    o.x = f2bf(v.x); o.y = f2bf(v.y); o.z = f2bf(v.z); o.w = f2bf(v.w);
    ((ushort4*)dst)[i] = o;
}

// Fused bf16 GEMM (C = A @ W^T + bias) + GroupNorm(32 groups of 64) + hardtanh.
// Tile 128 rows x 64 cols, BK=32. 4 waves, each 32 rows x 64 cols -> wave's 64
// cols == one GN group (in-wave shuffle reduction, no LDS round-trip).
// 1024 blocks = 4 blocks/CU (vs 2 at 128x128) for latency hiding.
// LDS XOR swizzle: granule (row,q) stored at q ^ ((row>>1)&3) -- staging stays
// coalesced (permutation within each row's 64B), fragment ds_read_b128 becomes
// 2-lanes-per-granule (free per m136) instead of 8-way conflicted.
__global__ __launch_bounds__(256, 4)
void gemm_gn_kernel(const unsigned short* __restrict__ A,  // [4096][2048] bf16
                    const unsigned short* __restrict__ W,  // [2048][2048] bf16
                    const float* __restrict__ bias,
                    const float* __restrict__ gnw,
                    const float* __restrict__ gnb,
                    float* __restrict__ out) {
    __shared__ __align__(16) unsigned short sA[128 * 32];  // 8 KB
    __shared__ __align__(16) unsigned short sB[64 * 32];   // 4 KB

    const int bc   = blockIdx.x;      // 0..31 col block (64 cols)
    const int br   = blockIdx.y;      // 0..31 row block (128 rows)
    const int t    = threadIdx.x;     // 0..255
    const int lane = t & 63;
    const int wave = t >> 6;
    const int c16  = lane & 15;
    const int quad = lane >> 4;

    f32x4 acc[2][4];
#pragma unroll
    for (int i = 0; i < 2; i++)
#pragma unroll
        for (int j = 0; j < 4; j++) acc[i][j] = (f32x4){0.f, 0.f, 0.f, 0.f};

    // ---- staging address precompute (granule = 8 elems = 16 B) ----
    // A granules: 512 (thread t handles g=t and g=t+256); B granules: 256 (g=t).
    // granule g: row=g>>2, q_l=g&3, loads global q_g = q_l ^ ((row>>1)&3).
    const int rowA = t >> 2;                       // 0..63 (second issue: +64, same swizzle)
    const int qgA  = (t & 3) ^ ((rowA >> 1) & 3);
    const unsigned short* gA = A + (size_t)(br * 128 + rowA) * C_IN + qgA * 8;
    const unsigned short* gB = W + (size_t)(bc * 64 + rowA) * C_IN + qgA * 8;

    // fragment-read swizzled granule (same for all i,j and both A/B)
    const int qs = quad ^ ((c16 >> 1) & 3);

    for (int k0 = 0; k0 < C_IN; k0 += 32) {
        __builtin_amdgcn_global_load_lds(
            (const __attribute__((address_space(1))) void*)(gA + k0),
            (__attribute__((address_space(3))) void*)(sA + t * 8), 16, 0, 0);
        __builtin_amdgcn_global_load_lds(
            (const __attribute__((address_space(1))) void*)(gA + (size_t)64 * C_IN + k0),
            (__attribute__((address_space(3))) void*)(sA + 2048 + t * 8), 16, 0, 0);
        __builtin_amdgcn_global_load_lds(
            (const __attribute__((address_space(1))) void*)(gB + k0),
            (__attribute__((address_space(3))) void*)(sB + t * 8), 16, 0, 0);
        __syncthreads();

        bf16x8 a[2], b[4];
#pragma unroll
        for (int i = 0; i < 2; i++)
            a[i] = *(const bf16x8*)(sA + (wave * 32 + i * 16 + c16) * 32 + qs * 8);
#pragma unroll
        for (int j = 0; j < 4; j++)
            b[j] = *(const bf16x8*)(sB + (j * 16 + c16) * 32 + qs * 8);
#pragma unroll
        for (int i = 0; i < 2; i++)
#pragma unroll
            for (int j = 0; j < 4; j++)
                acc[i][j] = __builtin_amdgcn_mfma_f32_16x16x32_bf16(a[i], b[j], acc[i][j], 0, 0, 0);
        __syncthreads();
    }

    // ---- epilogue: bias + GroupNorm + hardtanh ----
    // acc[i][j][r]: row = br*128 + wave*32 + i*16 + quad*4 + r,
    //               col = bc*64 + j*16 + c16. Wave's 64 cols = one group.
    const int colbase = bc * 64;
    const int rowbase = br * 128 + wave * 32;
    float bv[4], gw[4], gb[4];
#pragma unroll
    for (int j = 0; j < 4; j++) {
        int col = colbase + j * 16 + c16;
        bv[j] = bias[col];
        gw[j] = gnw[col];
        gb[j] = gnb[col];
    }
#pragma unroll
    for (int i = 0; i < 2; i++) {
#pragma unroll
        for (int r = 0; r < 4; r++) {
            float s = 0.f, ss = 0.f;
#pragma unroll
            for (int j = 0; j < 4; j++) {
                float v = acc[i][j][r] + bv[j];
                acc[i][j][r] = v;
                s += v;
                ss += v * v;
            }
#pragma unroll
            for (int m = 1; m < 16; m <<= 1) {
                s  += __shfl_xor(s, m, 64);
                ss += __shfl_xor(ss, m, 64);
            }
            float mean = s * (1.f / 64.f);
            float var  = ss * (1.f / 64.f) - mean * mean;
            float rstd = rsqrtf(var + EPS);
            int row = rowbase + i * 16 + quad * 4 + r;
            float* orow = out + (size_t)row * C_OUT;
#pragma unroll
            for (int j = 0; j < 4; j++) {
                float v = (acc[i][j][r] - mean) * rstd * gw[j] + gb[j];
                v = fminf(1.f, fmaxf(-1.f, v));
                orow[colbase + j * 16 + c16] = v;
            }
        }
    }
}

extern "C" void kernel_launch(void* const* d_in, const int* in_sizes, int n_in,
                              void* d_out, int out_size, void* d_ws, size_t ws_size,
                              hipStream_t stream) {
    const float* x    = (const float*)d_in[0];   // [4096, 2048]
    const float* w    = (const float*)d_in[1];   // [2048, 2048]
    const float* bias = (const float*)d_in[2];   // [2048]
    const float* gnw  = (const float*)d_in[3];   // [2048]
    const float* gnb  = (const float*)d_in[4];   // [2048]
    float* out = (float*)d_out;

    unsigned short* xb = (unsigned short*)d_ws;                        // 16 MB
    unsigned short* wb = xb + (size_t)B_ROWS * C_IN;                   //  8 MB

    const int nx4 = B_ROWS * C_IN / 4;   // 2097152
    const int nw4 = C_OUT * C_IN / 4;    // 1048576
    cvt_f32_bf16_kernel<<<(nx4 + nw4 + 255) / 256, 256, 0, stream>>>(x, w, xb, wb, nx4, nw4);

    dim3 grid(C_OUT / 64, B_ROWS / 128);  // (32, 32) = 1024 blocks
    gemm_gn_kernel<<<grid, 256, 0, stream>>>(xb, wb, bias, gnw, gnb, out);
}

// Round 3
// 147.008 us; speedup vs baseline: 1.0826x; 1.0826x over previous
//
#include <hip/hip_runtime.h>
#include <stdint.h>

#define B_ROWS 4096
#define C_OUT  2048
#define C_IN   2048
#define EPS    1e-5f

typedef __attribute__((ext_vector_type(8))) short bf16x8;  // 8 bf16 = 4 VGPRs
typedef __attribute__((ext_vector_type(4))) float f32x4;

// RNE f32 -> bf16
__device__ __forceinline__ unsigned short f2bf(float f) {
    uint32_t u = __float_as_uint(f);
    uint32_t r = (u + 0x7fffu + ((u >> 16) & 1u)) >> 16;
    return (unsigned short)r;
}

// One launch converts both x and w (f32 -> bf16, float4-granular)
__global__ void cvt_f32_bf16_kernel(const float* __restrict__ x,
                                    const float* __restrict__ w,
                                    unsigned short* __restrict__ xb,
                                    unsigned short* __restrict__ wb,
                                    int nx4, int nw4) {
    int i = blockIdx.x * blockDim.x + threadIdx.x;
    const float* src;
    unsigned short* dst;
    if (i < nx4) {
        src = x; dst = xb;
    } else {
        i -= nx4;
        if (i >= nw4) return;
        src = w; dst = wb;
    }
    float4 v = ((const float4*)src)[i];
    ushort4 o;
    o.x = f2bf(v.x); o.y = f2bf(v.y); o.z = f2bf(v.z); o.w = f2bf(v.w);
    ((ushort4*)dst)[i] = o;
}

// Fused bf16 GEMM (C = A @ W^T + bias) + GroupNorm(32 groups of 64) + hardtanh.
// Tile 128 rows x 64 cols, BK=64. 2 waves of 64x64 (acc 4x4 = best LDS reuse:
// 8 ds_read per 16 MFMA). Grid 1024 = 4 blocks/CU, barrier group only 2 waves.
// 32 MFMA per barrier-pair per wave (2x the R1 amortization).
// Swizzle (BK=64, 8 granules/row): (row,q) stored at q^(row&7); staging offset
// is issue-independent: q=(t&7)^((t>>3)&7); frag reads conflict-free.
__global__ __launch_bounds__(128, 2)
void gemm_gn_kernel(const unsigned short* __restrict__ A,  // [4096][2048] bf16
                    const unsigned short* __restrict__ W,  // [2048][2048] bf16
                    const float* __restrict__ bias,
                    const float* __restrict__ gnw,
                    const float* __restrict__ gnb,
                    float* __restrict__ out) {
    __shared__ __align__(16) unsigned short sA[128 * 64];  // 16 KB
    __shared__ __align__(16) unsigned short sB[64 * 64];   //  8 KB

    const int bc   = blockIdx.x;      // 0..31 col block (64 cols)
    const int br   = blockIdx.y;      // 0..31 row block (128 rows)
    const int t    = threadIdx.x;     // 0..127
    const int lane = t & 63;
    const int wave = t >> 6;          // 0..1
    const int c16  = lane & 15;
    const int quad = lane >> 4;

    f32x4 acc[4][4];
#pragma unroll
    for (int i = 0; i < 4; i++)
#pragma unroll
        for (int j = 0; j < 4; j++) acc[i][j] = (f32x4){0.f, 0.f, 0.f, 0.f};

    // ---- staging addresses ----
    // LDS granule G = n*128 + t; row = G>>3 = n*16 + (t>>3); phys q' = G&7 = t&7;
    // holds global q = q' ^ (row&7) = (t&7) ^ ((t>>3)&7)  (issue-independent).
    const int r0 = t >> 3;                         // 0..15
    const int qo = ((t & 7) ^ (r0 & 7)) * 8;       // element offset within row's 64
    const unsigned short* gA = A + (size_t)(br * 128 + r0) * C_IN + qo;
    const unsigned short* gB = W + (size_t)(bc * 64 + r0) * C_IN + qo;

    // fragment-read: logical (row, q=sub*4+quad) lives at q' = q ^ (c16&7)
    const int cl7 = c16 & 7;

    for (int k0 = 0; k0 < C_IN; k0 += 64) {
#pragma unroll
        for (int n = 0; n < 8; n++)
            __builtin_amdgcn_global_load_lds(
                (const __attribute__((address_space(1))) void*)(gA + (size_t)(n * 16) * C_IN + k0),
                (__attribute__((address_space(3))) void*)(sA + n * 1024 + t * 8), 16, 0, 0);
#pragma unroll
        for (int n = 0; n < 4; n++)
            __builtin_amdgcn_global_load_lds(
                (const __attribute__((address_space(1))) void*)(gB + (size_t)(n * 16) * C_IN + k0),
                (__attribute__((address_space(3))) void*)(sB + n * 1024 + t * 8), 16, 0, 0);
        __syncthreads();

#pragma unroll
        for (int sub = 0; sub < 2; sub++) {
            const int qs = ((sub << 2) | quad) ^ cl7;  // physical granule in row
            bf16x8 a[4], b[4];
#pragma unroll
            for (int i = 0; i < 4; i++)
                a[i] = *(const bf16x8*)(sA + (wave * 64 + i * 16 + c16) * 64 + qs * 8);
#pragma unroll
            for (int j = 0; j < 4; j++)
                b[j] = *(const bf16x8*)(sB + (j * 16 + c16) * 64 + qs * 8);
#pragma unroll
            for (int i = 0; i < 4; i++)
#pragma unroll
                for (int j = 0; j < 4; j++)
                    acc[i][j] = __builtin_amdgcn_mfma_f32_16x16x32_bf16(a[i], b[j], acc[i][j], 0, 0, 0);
        }
        __syncthreads();
    }

    // ---- epilogue: bias + GroupNorm + hardtanh ----
    // acc[i][j][r]: row = br*128 + wave*64 + i*16 + quad*4 + r,
    //               col = bc*64 + j*16 + c16. Wave's 64 cols = one group.
    const int colbase = bc * 64;
    const int rowbase = br * 128 + wave * 64;
    float bv[4], gw[4], gb[4];
#pragma unroll
    for (int j = 0; j < 4; j++) {
        int col = colbase + j * 16 + c16;
        bv[j] = bias[col];
        gw[j] = gnw[col];
        gb[j] = gnb[col];
    }
#pragma unroll
    for (int i = 0; i < 4; i++) {
#pragma unroll
        for (int r = 0; r < 4; r++) {
            float s = 0.f, ss = 0.f;
#pragma unroll
            for (int j = 0; j < 4; j++) {
                float v = acc[i][j][r] + bv[j];
                acc[i][j][r] = v;
                s += v;
                ss += v * v;
            }
#pragma unroll
            for (int m = 1; m < 16; m <<= 1) {
                s  += __shfl_xor(s, m, 64);
                ss += __shfl_xor(ss, m, 64);
            }
            float mean = s * (1.f / 64.f);
            float var  = ss * (1.f / 64.f) - mean * mean;
            float rstd = rsqrtf(var + EPS);
            int row = rowbase + i * 16 + quad * 4 + r;
            float* orow = out + (size_t)row * C_OUT;
#pragma unroll
            for (int j = 0; j < 4; j++) {
                float v = (acc[i][j][r] - mean) * rstd * gw[j] + gb[j];
                v = fminf(1.f, fmaxf(-1.f, v));
                orow[colbase + j * 16 + c16] = v;
            }
        }
    }
}

extern "C" void kernel_launch(void* const* d_in, const int* in_sizes, int n_in,
                              void* d_out, int out_size, void* d_ws, size_t ws_size,
                              hipStream_t stream) {
    const float* x    = (const float*)d_in[0];   // [4096, 2048]
    const float* w    = (const float*)d_in[1];   // [2048, 2048]
    const float* bias = (const float*)d_in[2];   // [2048]
    const float* gnw  = (const float*)d_in[3];   // [2048]
    const float* gnb  = (const float*)d_in[4];   // [2048]
    float* out = (float*)d_out;

    unsigned short* xb = (unsigned short*)d_ws;                        // 16 MB
    unsigned short* wb = xb + (size_t)B_ROWS * C_IN;                   //  8 MB

    const int nx4 = B_ROWS * C_IN / 4;   // 2097152
    const int nw4 = C_OUT * C_IN / 4;    // 1048576
    cvt_f32_bf16_kernel<<<(nx4 + nw4 + 255) / 256, 256, 0, stream>>>(x, w, xb, wb, nx4, nw4);

    dim3 grid(C_OUT / 64, B_ROWS / 128);  // (32, 32) = 1024 blocks, 128 thr each
    gemm_gn_kernel<<<grid, 128, 0, stream>>>(xb, wb, bias, gnw, gnb, out);
}